// Round 7
// baseline (53.080 us; speedup 1.0000x reference)
//
#include <hip/hip_runtime.h>
#include <math.h>

#define BATCH  8192
#define DIM    128
#define NTREES 512
#define UNITS  8
#define RB 64                      // batch rows per block
#define TB 64                      // trees per block
#define NROWBLK (BATCH/RB)         // 128
#define NTREEBLK (NTREES/TB)       // 8

typedef __attribute__((ext_vector_type(8))) __bf16 bf16x8;
typedef __attribute__((ext_vector_type(4))) float f32x4;

static __device__ inline unsigned short f2bf(float v) {
  __bf16 h = (__bf16)v;
  return *(unsigned short*)&h;
}

// ---------------------------------------------------------------------------
// Fused prep.  New tree=G layout:
//  W A-fragment subtile S=(tb*4+sub)*4+w holds 16 slots = 4 trees x 4 depths;
//  M-tile p is the DEPTH-half (p=0: d0-3, p=1: d4-7, d6/7 zero).  A-row
//  ln = (tree&3)*4 + (d&3).  GEMM2 K-bijection: k=ks*32+G*8+j <->
//  (tree=G, leaf = j | (ks<<3) | (half<<5)), two halves of 32 leaves.
// ---------------------------------------------------------------------------
__global__ __launch_bounds__(128) void prep_all(
    const float* __restrict__ logits, const float* __restrict__ thr,
    const float* __restrict__ logtemp, const float* __restrict__ inputs,
    const float* __restrict__ resp,
    unsigned short* __restrict__ Wfrag, unsigned short* __restrict__ Ximg,
    unsigned short* __restrict__ Rb, float* __restrict__ biasPad)
{
  const int b = blockIdx.x, tid = threadIdx.x;
  if (b < 4096) {
    const int t = b >> 3, d = b & 7;
    const int tb = t >> 6, sub = (t >> 4) & 3, w = (t >> 2) & 3, tq = t & 3;
    const int p = d >> 2, dloc = d & 3;
    const int ln = tq * 4 + dloc;
    const int S = (tb * 4 + sub) * 4 + w;
    const int i = tid;                       // dim index = k
    const int ks = i >> 5, G = (i >> 3) & 3, j = i & 7;
    const int lane = G * 16 + ln;
    const size_t wi = ((size_t)((S * 2 + p) * 4 + ks) * 64 + lane) * 8 + j;
    if (d >= 6) {
      Wfrag[wi] = 0;
      if (tid == 0) biasPad[t * 8 + d] = 0.f;
      return;
    }
    __shared__ float z[128], rc[128], rs[128];
    float zi = logits[((size_t)tid * NTREES + t) * 6 + d];
    z[tid] = zi;
    __syncthreads();
    float k = 0.f, Ssum = 0.f;
    for (int q = 0; q < 128; ++q) {
      float zq = z[q];
      if (zq >= zi) { k += 1.f; Ssum += zq; }
    }
    bool sup = (1.f + k * zi) > Ssum;
    rc[tid] = sup ? 1.f : 0.f;
    rs[tid] = sup ? zi : 0.f;
    __syncthreads();
    for (int off = 64; off > 0; off >>= 1) {
      if (tid < off) { rc[tid] += rc[tid + off]; rs[tid] += rs[tid + off]; }
      __syncthreads();
    }
    float tau = (rs[0] - 1.f) / rc[0];
    float et = expf(-logtemp[t*6 + d]);
    Wfrag[wi] = f2bf(fmaxf(zi - tau, 0.f) * et);
    if (tid == 0) biasPad[t*8 + d] = -thr[t*6 + d] * et;
  } else if (b < 12288) {
    const int r = b - 4096;
    float v = inputs[(size_t)r * DIM + tid];
    int col = ((tid * 2) ^ ((r & 7) << 4)) >> 1;
    Ximg[(size_t)r * DIM + col] = f2bf(v);
  } else {
    const int idx = (b - 12288) * 128 + tid;         // < 524288
    const int j = idx & 7, lane = (idx >> 3) & 63;
    const int ks = (idx >> 9) & 3, half = (idx >> 11) & 1, S = idx >> 12;
    const int G = lane >> 4, u = lane & 15;
    const int tree = S * 4 + G;
    const int leaf = j | (ks << 3) | (half << 5);
    float v = (u < UNITS) ? resp[((size_t)tree*UNITS + u)*64 + leaf] : 0.f;
    Rb[idx] = f2bf(v);
  }
}

// ---------------------------------------------------------------------------
// Main: 64 batch rows x 64 trees per block, 4 waves, grid 1024, tb = XCD.
// Per (sub,nt): 8 GEMM1 MFMA -> fd straight from c1 (tree=G, NO shuffles),
// gates/leaf products in-register, 8 GEMM2 MFMA.  No barriers in main loop.
// ---------------------------------------------------------------------------
__global__ __launch_bounds__(256, 2) void odt_main(
    const unsigned short* __restrict__ Ximg, const unsigned short* __restrict__ Wfrag,
    const float* __restrict__ biasPad, const unsigned short* __restrict__ Rb,
    float* __restrict__ partial)
{
  __shared__ __align__(16) char pool[18432];
  char* Xl = pool;                        // 16384 B
  float* biasl = (float*)(pool + 16384);  // 2048 B (512 floats)
  float* outred = (float*)pool;           // aliases Xl after final barrier (8 KB)

  const int tid = threadIdx.x;
  const int lane = tid & 63;
  const int w = tid >> 6;       // wave 0..3
  const int G = lane >> 4;      // 0..3  == this lane's tree within the quad
  const int ln = lane & 15;

  // XCD swizzle: tb = xcd (8 tree-blocks over 8 XCDs), bx = wg>>3
  const int wg = blockIdx.x;
  const int tb = wg & 7;
  const int bx = wg >> 3;

  {
    const float4* src = (const float4*)(Ximg + (size_t)bx * RB * DIM);
    float4* dst = (float4*)Xl;
    #pragma unroll
    for (int it = 0; it < 4; ++it) dst[tid + it * 256] = src[tid + it * 256];
  }
  biasl[tid]       = biasPad[(size_t)tb * 512 + tid];
  biasl[tid + 256] = biasPad[(size_t)tb * 512 + 256 + tid];
  __syncthreads();

  f32x4 out[4];
  #pragma unroll
  for (int nt = 0; nt < 4; ++nt)
    #pragma unroll
    for (int r = 0; r < 4; ++r) out[nt][r] = 0.f;

  #pragma unroll 1
  for (int sub = 0; sub < 4; ++sub) {
    const int S = (tb*4 + sub)*4 + w;
    const bf16x8* wf = (const bf16x8*)Wfrag + (size_t)S * 8 * 64;
    const bf16x8* rb = (const bf16x8*)Rb   + (size_t)S * 8 * 64;
    bf16x8 Afr[2][4], B2[2][4];
    #pragma unroll
    for (int p = 0; p < 2; ++p)
      #pragma unroll
      for (int ks = 0; ks < 4; ++ks) {
        Afr[p][ks] = wf[(p*4 + ks)*64 + lane];
        B2[p][ks]  = rb[(p*4 + ks)*64 + lane];
      }
    // bias for this lane's tree (local index sub*16 + w*4 + G)
    const int tl8 = (sub*16 + w*4 + G) * 8;
    float bv[6];
    #pragma unroll
    for (int d = 0; d < 6; ++d) bv[d] = biasl[tl8 + d];

    #pragma unroll
    for (int nt = 0; nt < 4; ++nt) {
      bf16x8 Bfr[4];
      #pragma unroll
      for (int ks = 0; ks < 4; ++ks) {
        int row = nt*16 + ln;
        int byte = row*256 + ((ks*64 + G*16) ^ ((row & 7) << 4));
        Bfr[ks] = *(const bf16x8*)(Xl + byte);
      }
      f32x4 c1[2];
      #pragma unroll
      for (int p = 0; p < 2; ++p)
        #pragma unroll
        for (int r = 0; r < 4; ++r) c1[p][r] = 0.f;
      #pragma unroll
      for (int ks = 0; ks < 4; ++ks)
        c1[0] = __builtin_amdgcn_mfma_f32_16x16x32_bf16(Afr[0][ks], Bfr[ks], c1[0], 0,0,0);
      #pragma unroll
      for (int ks = 0; ks < 4; ++ks)
        c1[1] = __builtin_amdgcn_mfma_f32_16x16x32_bf16(Afr[1][ks], Bfr[ks], c1[1], 0,0,0);

      // fd: own tree's 6 depths, straight from the accumulators (NO shuffle)
      float fd[6] = { c1[0][0], c1[0][1], c1[0][2], c1[0][3], c1[1][0], c1[1][1] };
      float s[6], om[6];
      #pragma unroll
      for (int d = 0; d < 6; ++d) {
        float tl = fd[d] + bv[d];
        float sv = fminf(fmaxf(0.5f + 0.5f*tl, 0.f), 1.f);
        s[d] = sv; om[d] = 1.f - sv;
      }
      // leaf bits: j->d0-2, ks&1->d3, ks>>1->d4, half->d5
      float q00 = s[0]*s[1],  q10 = om[0]*s[1];
      float q01 = s[0]*om[1], q11 = om[0]*om[1];
      float p3[8];
      p3[0]=q00*s[2];  p3[1]=q10*s[2];  p3[2]=q01*s[2];  p3[3]=q11*s[2];
      p3[4]=q00*om[2]; p3[5]=q10*om[2]; p3[6]=q01*om[2]; p3[7]=q11*om[2];
      float c34[4];
      c34[0] = s[3]*s[4];  c34[1] = om[3]*s[4];
      c34[2] = s[3]*om[4]; c34[3] = om[3]*om[4];
      float c345[2][4];
      #pragma unroll
      for (int ks = 0; ks < 4; ++ks) {
        c345[0][ks] = c34[ks] * s[5];
        c345[1][ks] = c34[ks] * om[5];
      }
      #pragma unroll
      for (int h = 0; h < 2; ++h)
        #pragma unroll
        for (int ks = 0; ks < 4; ++ks) {
          bf16x8 A;
          #pragma unroll
          for (int j = 0; j < 8; ++j) A[j] = (__bf16)(c345[h][ks] * p3[j]);
          out[nt] = __builtin_amdgcn_mfma_f32_16x16x32_bf16(A, B2[h][ks], out[nt], 0,0,0);
        }
    }
  }

  // ---- cross-wave reduction (outred aliases Xl; all Xl reads done) ----
  __syncthreads();
  if (ln < UNITS) {
    #pragma unroll
    for (int nt = 0; nt < 4; ++nt)
      #pragma unroll
      for (int r = 0; r < 4; ++r)
        outred[((size_t)w*64 + nt*16 + 4*G + r)*8 + ln] = out[nt][r];
  }
  __syncthreads();
  #pragma unroll
  for (int v = 0; v < 2; ++v) {
    int e = tid + v*256;               // 0..511 = row*8+u
    int row = e >> 3, u = e & 7;
    float sum = outred[(0*64 + row)*8 + u]
              + outred[(1*64 + row)*8 + u]
              + outred[(2*64 + row)*8 + u]
              + outred[(3*64 + row)*8 + u];
    partial[((size_t)tb*BATCH + bx*RB + row)*8 + u] = sum;
  }
}

// ---------------------------------------------------------------------------
// reduce over the 8 tree-blocks (float4-vectorized), scale by 1/512
// ---------------------------------------------------------------------------
__global__ __launch_bounds__(256) void odt_reduce(
    const f32x4* __restrict__ partial, f32x4* __restrict__ out)
{
  int i = blockIdx.x*256 + threadIdx.x;   // 0..16383 (x4 floats)
  f32x4 sv;
  #pragma unroll
  for (int r = 0; r < 4; ++r) sv[r] = 0.f;
  #pragma unroll
  for (int t = 0; t < NTREEBLK; ++t) {
    f32x4 v = partial[(size_t)t * (BATCH*UNITS/4) + i];
    #pragma unroll
    for (int r = 0; r < 4; ++r) sv[r] += v[r];
  }
  #pragma unroll
  for (int r = 0; r < 4; ++r) sv[r] *= (1.f/NTREES);
  out[i] = sv;
}

extern "C" void kernel_launch(void* const* d_in, const int* in_sizes, int n_in,
                              void* d_out, int out_size, void* d_ws, size_t ws_size,
                              hipStream_t stream)
{
  const float* inputs   = (const float*)d_in[0];
  const float* logits   = (const float*)d_in[1];
  const float* thr      = (const float*)d_in[2];
  const float* logtemp  = (const float*)d_in[3];
  const float* response = (const float*)d_in[4];
  float* out = (float*)d_out;

  char* ws = (char*)d_ws;
  unsigned short* Wfrag = (unsigned short*)(ws);                // 1 MB
  unsigned short* Ximg  = (unsigned short*)(ws + (1<<20));      // 2 MB
  unsigned short* Rb    = (unsigned short*)(ws + (3<<20));      // 1 MB
  float* biasPad        = (float*)(ws + (4<<20));               // 16 KB
  float* partial        = (float*)(ws + (4<<20) + (1<<14));     // 8 x 4 MB

  hipLaunchKernelGGL(prep_all, dim3(16384), dim3(128), 0, stream,
                     logits, thr, logtemp, inputs, response,
                     Wfrag, Ximg, Rb, biasPad);
  hipLaunchKernelGGL(odt_main, dim3(NROWBLK * NTREEBLK), dim3(256), 0, stream,
                     Ximg, Wfrag, biasPad, Rb, partial);
  hipLaunchKernelGGL(odt_reduce, dim3(BATCH * UNITS / 4 / 256), dim3(256), 0, stream,
                     (const f32x4*)partial, (f32x4*)out);
}

// Round 8
// 46.544 us; speedup vs baseline: 1.1404x; 1.1404x over previous
//
#include <hip/hip_runtime.h>
#include <math.h>

#define BATCH  8192
#define DIM    128
#define NTREES 512
#define UNITS  8
#define RB 64                      // batch rows per block
#define TB 64                      // trees per block
#define NROWBLK (BATCH/RB)         // 128
#define NTREEBLK (NTREES/TB)       // 8

typedef __attribute__((ext_vector_type(8))) __bf16 bf16x8;
typedef __attribute__((ext_vector_type(4))) float f32x4;
typedef __attribute__((ext_vector_type(2))) float f32x2;

static __device__ inline unsigned short f2bf(float v) {
  __bf16 h = (__bf16)v;
  return *(unsigned short*)&h;
}

// ---------------------------------------------------------------------------
// Fused prep.  tree=G layout:
//  W A-fragment subtile S=(tb*4+sub)*4+w holds 16 slots = 4 trees x 4 depths;
//  M-tile p is the DEPTH-half (p=0: d0-3, p=1: d4-7, d6/7 zero).  A-row
//  ln = (tree&3)*4 + (d&3).  GEMM2 K-bijection: k=ks*32+G*8+j <->
//  (tree=G, leaf = j | (ks<<3) | (half<<5)), two halves of 32 leaves.
// ---------------------------------------------------------------------------
__global__ __launch_bounds__(128) void prep_all(
    const float* __restrict__ logits, const float* __restrict__ thr,
    const float* __restrict__ logtemp, const float* __restrict__ inputs,
    const float* __restrict__ resp,
    unsigned short* __restrict__ Wfrag, unsigned short* __restrict__ Ximg,
    unsigned short* __restrict__ Rb, float* __restrict__ biasPad)
{
  const int b = blockIdx.x, tid = threadIdx.x;
  if (b < 4096) {
    const int t = b >> 3, d = b & 7;
    const int tb = t >> 6, sub = (t >> 4) & 3, w = (t >> 2) & 3, tq = t & 3;
    const int p = d >> 2, dloc = d & 3;
    const int ln = tq * 4 + dloc;
    const int S = (tb * 4 + sub) * 4 + w;
    const int i = tid;                       // dim index = k
    const int ks = i >> 5, G = (i >> 3) & 3, j = i & 7;
    const int lane = G * 16 + ln;
    const size_t wi = ((size_t)((S * 2 + p) * 4 + ks) * 64 + lane) * 8 + j;
    if (d >= 6) {
      Wfrag[wi] = 0;
      if (tid == 0) biasPad[t * 8 + d] = 0.f;
      return;
    }
    __shared__ float z[128], rc[128], rs[128];
    float zi = logits[((size_t)tid * NTREES + t) * 6 + d];
    z[tid] = zi;
    __syncthreads();
    float k = 0.f, Ssum = 0.f;
    for (int q = 0; q < 128; ++q) {
      float zq = z[q];
      if (zq >= zi) { k += 1.f; Ssum += zq; }
    }
    bool sup = (1.f + k * zi) > Ssum;
    rc[tid] = sup ? 1.f : 0.f;
    rs[tid] = sup ? zi : 0.f;
    __syncthreads();
    for (int off = 64; off > 0; off >>= 1) {
      if (tid < off) { rc[tid] += rc[tid + off]; rs[tid] += rs[tid + off]; }
      __syncthreads();
    }
    float tau = (rs[0] - 1.f) / rc[0];
    float et = expf(-logtemp[t*6 + d]);
    Wfrag[wi] = f2bf(fmaxf(zi - tau, 0.f) * et);
    if (tid == 0) biasPad[t*8 + d] = -thr[t*6 + d] * et;
  } else if (b < 12288) {
    const int r = b - 4096;
    float v = inputs[(size_t)r * DIM + tid];
    int col = ((tid * 2) ^ ((r & 7) << 4)) >> 1;
    Ximg[(size_t)r * DIM + col] = f2bf(v);
  } else {
    const int idx = (b - 12288) * 128 + tid;         // < 524288
    const int j = idx & 7, lane = (idx >> 3) & 63;
    const int ks = (idx >> 9) & 3, half = (idx >> 11) & 1, S = idx >> 12;
    const int G = lane >> 4, u = lane & 15;
    const int tree = S * 4 + G;
    const int leaf = j | (ks << 3) | (half << 5);
    float v = (u < UNITS) ? resp[((size_t)tree*UNITS + u)*64 + leaf] : 0.f;
    Rb[idx] = f2bf(v);
  }
}

// ---------------------------------------------------------------------------
// Main: 64 batch rows x 64 trees per block, 4 waves, grid 1024, tb = XCD.
// launch_bounds(256,3): cap ~170 VGPR -> 3 waves/SIMD without spilling the
// ~150-reg live set (Afr+B2 resident, epilogue working set).
// ---------------------------------------------------------------------------
__global__ __launch_bounds__(256, 3) void odt_main(
    const unsigned short* __restrict__ Ximg, const unsigned short* __restrict__ Wfrag,
    const float* __restrict__ biasPad, const unsigned short* __restrict__ Rb,
    float* __restrict__ partial)
{
  __shared__ __align__(16) char pool[18432];
  char* Xl = pool;                        // 16384 B
  float* biasl = (float*)(pool + 16384);  // 2048 B (512 floats)
  float* outred = (float*)pool;           // aliases Xl after final barrier (8 KB)

  const int tid = threadIdx.x;
  const int lane = tid & 63;
  const int w = tid >> 6;       // wave 0..3
  const int G = lane >> 4;      // 0..3  == this lane's tree within the quad
  const int ln = lane & 15;

  // XCD swizzle: tb = xcd (8 tree-blocks over 8 XCDs), bx = wg>>3
  const int wg = blockIdx.x;
  const int tb = wg & 7;
  const int bx = wg >> 3;

  {
    const float4* src = (const float4*)(Ximg + (size_t)bx * RB * DIM);
    float4* dst = (float4*)Xl;
    #pragma unroll
    for (int it = 0; it < 4; ++it) dst[tid + it * 256] = src[tid + it * 256];
  }
  biasl[tid]       = biasPad[(size_t)tb * 512 + tid];
  biasl[tid + 256] = biasPad[(size_t)tb * 512 + 256 + tid];
  __syncthreads();

  f32x4 out[4];
  #pragma unroll
  for (int nt = 0; nt < 4; ++nt)
    #pragma unroll
    for (int r = 0; r < 4; ++r) out[nt][r] = 0.f;

  #pragma unroll 1
  for (int sub = 0; sub < 4; ++sub) {
    const int S = (tb*4 + sub)*4 + w;
    const bf16x8* wf = (const bf16x8*)Wfrag + (size_t)S * 8 * 64;
    const bf16x8* rb = (const bf16x8*)Rb   + (size_t)S * 8 * 64;
    bf16x8 Afr[2][4], B2[2][4];
    #pragma unroll
    for (int p = 0; p < 2; ++p)
      #pragma unroll
      for (int ks = 0; ks < 4; ++ks) {
        Afr[p][ks] = wf[(p*4 + ks)*64 + lane];
        B2[p][ks]  = rb[(p*4 + ks)*64 + lane];
      }
    // bias for this lane's tree (local index sub*16 + w*4 + G)
    const int tl8 = (sub*16 + w*4 + G) * 8;
    float bv[6];
    #pragma unroll
    for (int d = 0; d < 6; ++d) bv[d] = biasl[tl8 + d];

    #pragma unroll
    for (int nt = 0; nt < 4; ++nt) {
      bf16x8 Bfr[4];
      #pragma unroll
      for (int ks = 0; ks < 4; ++ks) {
        int row = nt*16 + ln;
        int byte = row*256 + ((ks*64 + G*16) ^ ((row & 7) << 4));
        Bfr[ks] = *(const bf16x8*)(Xl + byte);
      }
      f32x4 c1[2];
      #pragma unroll
      for (int p = 0; p < 2; ++p)
        #pragma unroll
        for (int r = 0; r < 4; ++r) c1[p][r] = 0.f;
      #pragma unroll
      for (int ks = 0; ks < 4; ++ks)
        c1[0] = __builtin_amdgcn_mfma_f32_16x16x32_bf16(Afr[0][ks], Bfr[ks], c1[0], 0,0,0);
      #pragma unroll
      for (int ks = 0; ks < 4; ++ks)
        c1[1] = __builtin_amdgcn_mfma_f32_16x16x32_bf16(Afr[1][ks], Bfr[ks], c1[1], 0,0,0);

      // fd: own tree's 6 depths, straight from the accumulators (NO shuffle)
      float fd[6] = { c1[0][0], c1[0][1], c1[0][2], c1[0][3], c1[1][0], c1[1][1] };
      float s[6], om[6];
      #pragma unroll
      for (int d = 0; d < 6; ++d) {
        float tl = fd[d] + bv[d];
        float sv = fminf(fmaxf(0.5f + 0.5f*tl, 0.f), 1.f);
        s[d] = sv; om[d] = 1.f - sv;
      }
      // leaf bits: j->d0-2, ks&1->d3, ks>>1->d4, half->d5
      float q00 = s[0]*s[1],  q10 = om[0]*s[1];
      float q01 = s[0]*om[1], q11 = om[0]*om[1];
      // p3 as float2 pairs to encourage v_pk_mul_f32 / v_cvt_pk_bf16_f32
      f32x2 p3p[4];
      p3p[0] = (f32x2){q00*s[2],  q10*s[2]};
      p3p[1] = (f32x2){q01*s[2],  q11*s[2]};
      p3p[2] = (f32x2){q00*om[2], q10*om[2]};
      p3p[3] = (f32x2){q01*om[2], q11*om[2]};
      float c34[4];
      c34[0] = s[3]*s[4];  c34[1] = om[3]*s[4];
      c34[2] = s[3]*om[4]; c34[3] = om[3]*om[4];

      #pragma unroll
      for (int h = 0; h < 2; ++h) {
        const float g5 = h ? om[5] : s[5];
        #pragma unroll
        for (int ks = 0; ks < 4; ++ks) {
          const float c = c34[ks] * g5;
          bf16x8 A;
          #pragma unroll
          for (int jp = 0; jp < 4; ++jp) {
            f32x2 pr = c * p3p[jp];             // v_pk_mul_f32
            A[jp*2]   = (__bf16)pr[0];          // pairs -> v_cvt_pk_bf16_f32
            A[jp*2+1] = (__bf16)pr[1];
          }
          out[nt] = __builtin_amdgcn_mfma_f32_16x16x32_bf16(A, B2[h][ks], out[nt], 0,0,0);
        }
      }
    }
  }

  // ---- cross-wave reduction (outred aliases Xl; all Xl reads done) ----
  __syncthreads();
  if (ln < UNITS) {
    #pragma unroll
    for (int nt = 0; nt < 4; ++nt)
      #pragma unroll
      for (int r = 0; r < 4; ++r)
        outred[((size_t)w*64 + nt*16 + 4*G + r)*8 + ln] = out[nt][r];
  }
  __syncthreads();
  #pragma unroll
  for (int v = 0; v < 2; ++v) {
    int e = tid + v*256;               // 0..511 = row*8+u
    int row = e >> 3, u = e & 7;
    float sum = outred[(0*64 + row)*8 + u]
              + outred[(1*64 + row)*8 + u]
              + outred[(2*64 + row)*8 + u]
              + outred[(3*64 + row)*8 + u];
    partial[((size_t)tb*BATCH + bx*RB + row)*8 + u] = sum;
  }
}

// ---------------------------------------------------------------------------
// reduce over the 8 tree-blocks (float4-vectorized), scale by 1/512
// ---------------------------------------------------------------------------
__global__ __launch_bounds__(256) void odt_reduce(
    const f32x4* __restrict__ partial, f32x4* __restrict__ out)
{
  int i = blockIdx.x*256 + threadIdx.x;   // 0..16383 (x4 floats)
  f32x4 sv;
  #pragma unroll
  for (int r = 0; r < 4; ++r) sv[r] = 0.f;
  #pragma unroll
  for (int t = 0; t < NTREEBLK; ++t) {
    f32x4 v = partial[(size_t)t * (BATCH*UNITS/4) + i];
    #pragma unroll
    for (int r = 0; r < 4; ++r) sv[r] += v[r];
  }
  #pragma unroll
  for (int r = 0; r < 4; ++r) sv[r] *= (1.f/NTREES);
  out[i] = sv;
}

extern "C" void kernel_launch(void* const* d_in, const int* in_sizes, int n_in,
                              void* d_out, int out_size, void* d_ws, size_t ws_size,
                              hipStream_t stream)
{
  const float* inputs   = (const float*)d_in[0];
  const float* logits   = (const float*)d_in[1];
  const float* thr      = (const float*)d_in[2];
  const float* logtemp  = (const float*)d_in[3];
  const float* response = (const float*)d_in[4];
  float* out = (float*)d_out;

  char* ws = (char*)d_ws;
  unsigned short* Wfrag = (unsigned short*)(ws);                // 1 MB
  unsigned short* Ximg  = (unsigned short*)(ws + (1<<20));      // 2 MB
  unsigned short* Rb    = (unsigned short*)(ws + (3<<20));      // 1 MB
  float* biasPad        = (float*)(ws + (4<<20));               // 16 KB
  float* partial        = (float*)(ws + (4<<20) + (1<<14));     // 8 x 256 KB... (8x4MB region)

  hipLaunchKernelGGL(prep_all, dim3(16384), dim3(128), 0, stream,
                     logits, thr, logtemp, inputs, response,
                     Wfrag, Ximg, Rb, biasPad);
  hipLaunchKernelGGL(odt_main, dim3(NROWBLK * NTREEBLK), dim3(256), 0, stream,
                     Ximg, Wfrag, biasPad, Rb, partial);
  hipLaunchKernelGGL(odt_reduce, dim3(BATCH * UNITS / 4 / 256), dim3(256), 0, stream,
                     (const f32x4*)partial, (f32x4*)out);
}